// Round 5
// baseline (98.607 us; speedup 1.0000x reference)
//
#include <hip/hip_runtime.h>
#include <math.h>

// LDDMM variational RHS, Gaussian kernel sigma=0.1, B=1, N=8192, D=3.
// out[0:N*3]     = dmom_i = (1/sig^2) * (x_i * sum_j W_ij - sum_j W_ij x_j)
// out[N*3:2*N*3] = dcp_i  = sum_j K_ij p_j
// K_ij = exp(-|x_i-x_j|^2/(2 sig^2)), W_ij = K_ij*(p_i.p_j), p=clamp(mom,-1,1)
//
// R5 model (closes exactly on R2's counters): partial is VALU+trans
// ISSUE-bound at SCLK ~1.4 GHz (DVFS parked low: 40us compute bursts
// between 43us memory fills). R2: 33.5k VALU-cy + 8.2k exp-cy = 41.7k
// = 70% of 59.8k cy @1.4GHz over 42.7us -- exact. The 43.5us
// fillBufferAligned is the harness 0xAA-poisoning all of d_ws: fixed tax.
// Lever = fewer issue slots: Mi=4 i-points/thread (amortizes LDS waits ->
// kills the 30% stall), xj pre-scaled by M2COEF in staging (15 ops/pair,
// wx un-scaled in reduce epilogue), prep folded into staging (2 dispatches).
// Predicted partial: 38.9k cy/SIMD = 16.2us @2.4GHz / ~28us @1.4GHz.

#define NPTS 8192
#define N3   (NPTS * 3)
#define BI   256
#define MI   4                       // i-points per thread
#define IBLK (NPTS / (BI * MI))      // 8 i-blocks
#define JC   128
#define JLEN (NPTS / JC)             // 64 j's per chunk

// exp(-d2/(2*0.1^2)) = exp2(d2 * (-50*log2(e)))
#define COEF    (-72.134752044448170f)
#define M2COEF  (144.269504088896340f)     // -2*COEF
#define UNSC100 (0.69314718055994531f)     // 100 / M2COEF

#define WS_NEEDED ((size_t)JC * NPTS * 8 * sizeof(float))  // 33.5 MB

__device__ __forceinline__ float fast_exp2(float x) {
#if __has_builtin(__builtin_amdgcn_exp2f)
    return __builtin_amdgcn_exp2f(x);
#else
    return exp2f(x);
#endif
}

__device__ __forceinline__ float clamp1(float v) {
    return fminf(fmaxf(v, -1.0f), 1.0f);
}

// ws layout: ws[((c*NPTS)+i)*8 + k], k=0..3: dcp0,dcp1,dcp2,wsum
//                                    k=4..7: wxs0,wxs1,wxs2,0  (wxs = M2COEF*wx)
__global__ __launch_bounds__(BI, 4) void lddmm_partial(const float* __restrict__ mom,
                                                       const float* __restrict__ cp,
                                                       float* __restrict__ ws) {
    const int ib = (int)blockIdx.x / JC;
    const int jc = (int)blockIdx.x % JC;
    const int t  = (int)threadIdx.x;
    const int i0 = ib * (BI * MI) + t;   // 4 i's per thread, stride BI

    // i-side data (clamp + coef hoisted; 4 points)
    float xi0[MI], xi1[MI], xi2[MI], ci[MI], pi0[MI], pi1[MI], pi2[MI];
#pragma unroll
    for (int m = 0; m < MI; ++m) {
        const int i = i0 + m * BI;
        const float x0 = cp[i * 3 + 0], x1 = cp[i * 3 + 1], x2 = cp[i * 3 + 2];
        xi0[m] = x0; xi1[m] = x1; xi2[m] = x2;
        ci[m]  = COEF * (x0 * x0 + x1 * x1 + x2 * x2);
        pi0[m] = clamp1(mom[i * 3 + 0]);
        pi1[m] = clamp1(mom[i * 3 + 1]);
        pi2[m] = clamp1(mom[i * 3 + 2]);
    }

    // Stage j-chunk: shx = {M2COEF*xj, cj}, shp = {pj clamped, 0}
    __shared__ float4 shx[JLEN];
    __shared__ float4 shp[JLEN];
    if (t < JLEN) {
        const int j = jc * JLEN + t;
        const float x0 = cp[j * 3 + 0], x1 = cp[j * 3 + 1], x2 = cp[j * 3 + 2];
        shx[t] = make_float4(M2COEF * x0, M2COEF * x1, M2COEF * x2,
                             COEF * (x0 * x0 + x1 * x1 + x2 * x2));
        shp[t] = make_float4(clamp1(mom[j * 3 + 0]), clamp1(mom[j * 3 + 1]),
                             clamp1(mom[j * 3 + 2]), 0.0f);
    }
    __syncthreads();

    float dcp0[MI], dcp1[MI], dcp2[MI], wsum[MI], wx0[MI], wx1[MI], wx2[MI];
#pragma unroll
    for (int m = 0; m < MI; ++m) {
        dcp0[m] = 0.f; dcp1[m] = 0.f; dcp2[m] = 0.f; wsum[m] = 0.f;
        wx0[m] = 0.f; wx1[m] = 0.f; wx2[m] = 0.f;
    }

#pragma unroll 8
    for (int jj = 0; jj < JLEN; ++jj) {
        const float4 xj = shx[jj];   // wave-uniform -> broadcast, no conflicts
        const float4 pj = shp[jj];
#pragma unroll
        for (int m = 0; m < MI; ++m) {
            // arg = ci + cj + dot(xi, M2COEF*xj) = COEF * d2   (4 VALU)
            float arg = ci[m] + xj.w;
            arg = fmaf(xi2[m], xj.z, arg);
            arg = fmaf(xi1[m], xj.y, arg);
            arg = fmaf(xi0[m], xj.x, arg);
            const float K = fast_exp2(arg);          // 1 trans
            float pd = pi0[m] * pj.x;                // 3 VALU
            pd = fmaf(pi1[m], pj.y, pd);
            pd = fmaf(pi2[m], pj.z, pd);
            const float W = K * pd;                  // 1 VALU
            dcp0[m] = fmaf(K, pj.x, dcp0[m]);        // 7 VALU accum
            dcp1[m] = fmaf(K, pj.y, dcp1[m]);
            dcp2[m] = fmaf(K, pj.z, dcp2[m]);
            wsum[m] += W;
            wx0[m] = fmaf(W, xj.x, wx0[m]);          // scaled by M2COEF
            wx1[m] = fmaf(W, xj.y, wx1[m]);
            wx2[m] = fmaf(W, xj.z, wx2[m]);
        }
    }

#pragma unroll
    for (int m = 0; m < MI; ++m) {
        float4* o = (float4*)(ws + ((size_t)(jc * NPTS) + (i0 + m * BI)) * 8);
        o[0] = make_float4(dcp0[m], dcp1[m], dcp2[m], wsum[m]);
        o[1] = make_float4(wx0[m], wx1[m], wx2[m], 0.0f);
    }
}

// 4 threads per i: sub=(cpart,half). Each sums JC/2 chunks of one float4,
// xor-2 combines chunk halves, xor-1 hands wsum from half0 to half1.
// dmom = 100*xi*wsum - (100/M2COEF)*wxs.
__global__ __launch_bounds__(256) void lddmm_reduce(const float* __restrict__ ws,
                                                    const float* __restrict__ cp,
                                                    float* __restrict__ out) {
    const int tid   = (int)blockIdx.x * 256 + (int)threadIdx.x;
    const int i     = tid >> 2;
    const int sub   = tid & 3;
    const int half  = sub & 1;
    const int cpart = sub >> 1;

    float4 acc = make_float4(0.f, 0.f, 0.f, 0.f);
    const int c0 = cpart * (JC / 2);
#pragma unroll 4
    for (int c = c0; c < c0 + JC / 2; ++c) {
        const float4 v = ((const float4*)(ws + ((size_t)(c * NPTS) + i) * 8))[half];
        acc.x += v.x; acc.y += v.y; acc.z += v.z; acc.w += v.w;
    }
    acc.x += __shfl_xor(acc.x, 2);
    acc.y += __shfl_xor(acc.y, 2);
    acc.z += __shfl_xor(acc.z, 2);
    acc.w += __shfl_xor(acc.w, 2);
    const float wsum = __shfl_xor(acc.w, 1);
    if (sub == 0) {
        out[N3 + i * 3 + 0] = acc.x;
        out[N3 + i * 3 + 1] = acc.y;
        out[N3 + i * 3 + 2] = acc.z;
    } else if (sub == 1) {
        const float xi0 = cp[i * 3 + 0];
        const float xi1 = cp[i * 3 + 1];
        const float xi2 = cp[i * 3 + 2];
        out[i * 3 + 0] = fmaf(100.0f * xi0, wsum, -UNSC100 * acc.x);
        out[i * 3 + 1] = fmaf(100.0f * xi1, wsum, -UNSC100 * acc.y);
        out[i * 3 + 2] = fmaf(100.0f * xi2, wsum, -UNSC100 * acc.z);
    }
}

// ---- fallback (atomics into d_out) if ws_size < WS_NEEDED ----
#define FJC   32
#define FJLEN (NPTS / FJC)
__global__ __launch_bounds__(BI) void lddmm_pairs_atomic(const float* __restrict__ mom,
                                                         const float* __restrict__ cp,
                                                         float* __restrict__ out) {
    const int ib = (int)blockIdx.x / FJC;
    const int jc = (int)blockIdx.x % FJC;
    const int t  = (int)threadIdx.x;
    const int i  = ib * BI + t;

    const float xi0 = cp[i * 3 + 0], xi1 = cp[i * 3 + 1], xi2 = cp[i * 3 + 2];
    const float pi0 = clamp1(mom[i * 3 + 0]), pi1 = clamp1(mom[i * 3 + 1]),
                pi2 = clamp1(mom[i * 3 + 2]);

    __shared__ float4 shx[FJLEN];
    __shared__ float4 shp[FJLEN];
    {
        const int j = jc * FJLEN + t;
        shx[t] = make_float4(cp[j * 3 + 0], cp[j * 3 + 1], cp[j * 3 + 2], 0.0f);
        shp[t] = make_float4(clamp1(mom[j * 3 + 0]), clamp1(mom[j * 3 + 1]),
                             clamp1(mom[j * 3 + 2]), 0.0f);
    }
    __syncthreads();

    float dcp0 = 0.f, dcp1 = 0.f, dcp2 = 0.f, wsum = 0.f, wx0 = 0.f, wx1 = 0.f, wx2 = 0.f;
#pragma unroll 4
    for (int jj = 0; jj < FJLEN; ++jj) {
        const float4 xj = shx[jj];
        const float4 pj = shp[jj];
        const float dx0 = xi0 - xj.x, dx1 = xi1 - xj.y, dx2 = xi2 - xj.z;
        const float d2  = dx0 * dx0 + dx1 * dx1 + dx2 * dx2;
        const float K   = fast_exp2(d2 * COEF);
        const float pd  = pi0 * pj.x + pi1 * pj.y + pi2 * pj.z;
        const float W   = K * pd;
        dcp0 += K * pj.x; dcp1 += K * pj.y; dcp2 += K * pj.z;
        wsum += W;
        wx0 += W * xj.x; wx1 += W * xj.y; wx2 += W * xj.z;
    }
    atomicAdd(&out[i * 3 + 0], 100.0f * (xi0 * wsum - wx0));
    atomicAdd(&out[i * 3 + 1], 100.0f * (xi1 * wsum - wx1));
    atomicAdd(&out[i * 3 + 2], 100.0f * (xi2 * wsum - wx2));
    atomicAdd(&out[N3 + i * 3 + 0], dcp0);
    atomicAdd(&out[N3 + i * 3 + 1], dcp1);
    atomicAdd(&out[N3 + i * 3 + 2], dcp2);
}

extern "C" void kernel_launch(void* const* d_in, const int* in_sizes, int n_in,
                              void* d_out, int out_size, void* d_ws, size_t ws_size,
                              hipStream_t stream) {
    const float* mom = (const float*)d_in[0];
    const float* cp  = (const float*)d_in[1];
    float* out = (float*)d_out;

    if (ws_size >= WS_NEEDED) {
        float* ws = (float*)d_ws;
        hipLaunchKernelGGL(lddmm_partial, dim3(IBLK * JC), dim3(BI), 0, stream, mom, cp, ws);
        hipLaunchKernelGGL(lddmm_reduce, dim3(NPTS * 4 / 256), dim3(256), 0, stream, ws, cp, out);
    } else {
        hipMemsetAsync(out, 0, (size_t)out_size * sizeof(float), stream);
        hipLaunchKernelGGL(lddmm_pairs_atomic, dim3((NPTS / BI) * FJC), dim3(BI), 0, stream, mom, cp, out);
    }
}

// Round 6
// 89.416 us; speedup vs baseline: 1.1028x; 1.1028x over previous
//
#include <hip/hip_runtime.h>
#include <math.h>

// LDDMM variational RHS, Gaussian kernel sigma=0.1, B=1, N=8192, D=3.
// out[0:N*3]     = dmom_i = (1/sig^2) * (x_i * sum_j W_ij - sum_j W_ij x_j)
// out[N*3:2*N*3] = dcp_i  = sum_j K_ij p_j
// K_ij = exp(-|x_i-x_j|^2/(2 sig^2)), W_ij = K_ij*(p_i.p_j), p=clamp(mom,-1,1)
//
// R6: partial is VALU-ISSUE-bound (~33k scalar-VALU cy/SIMD; R3-R5 all flat
// because none cut issue count). Lever: packed fp32 (VOP3P, gfx90a+
// hasPackedFP32Ops -> v_pk_fma_f32 at 2x fp32/lane/issue -- the 157 vs 78.6
// TF factor). Two i-points live in the two halves of each VGPR pair via
// ext_vector_type(2) + __builtin_elementwise_fma; j-values broadcast-splat
// (op_sel). Inner loop: 15 packed VALU + 2 v_exp per 128 pairs/wave-iter
// = ~46 cy vs ~134 before -> partial ~10us @2.4GHz, ~17us @1.4GHz.
// Harness's 268MB d_ws 0xAA re-poison (~44-48us fill) is a fixed tax.

#define NPTS 8192
#define N3   (NPTS * 3)
#define BI   256
#define IBLK (NPTS / (BI * 2))       // 16 i-blocks (2 i's per thread, packed)
#define JC   64
#define JLEN (NPTS / JC)             // 128 j's per chunk

// exp(-d2/(2*0.1^2)) = exp2(d2 * (-50*log2(e)))
#define COEF    (-72.134752044448170f)
#define M2COEF  (144.269504088896340f)     // -2*COEF
#define UNSC100 (0.69314718055994531f)     // 100 / M2COEF

#define WS_NEEDED ((size_t)JC * NPTS * 8 * sizeof(float))  // 16.78 MB

typedef float v2f __attribute__((ext_vector_type(2)));

__device__ __forceinline__ v2f vsplat(float s) { v2f r; r.x = s; r.y = s; return r; }

__device__ __forceinline__ v2f pkfma(v2f a, v2f b, v2f c) {
#if __has_builtin(__builtin_elementwise_fma)
    return __builtin_elementwise_fma(a, b, c);
#else
    v2f r; r.x = fmaf(a.x, b.x, c.x); r.y = fmaf(a.y, b.y, c.y); return r;
#endif
}

__device__ __forceinline__ float fast_exp2(float x) {
#if __has_builtin(__builtin_amdgcn_exp2f)
    return __builtin_amdgcn_exp2f(x);
#else
    return exp2f(x);
#endif
}

__device__ __forceinline__ float clamp1(float v) {
    return fminf(fmaxf(v, -1.0f), 1.0f);
}

// ws layout: ws[((c*NPTS)+i)*8 + k], k=0..3: dcp0,dcp1,dcp2,wsum
//                                    k=4..7: wxs0,wxs1,wxs2,0 (wxs = M2COEF*wx)
__global__ __launch_bounds__(BI, 4) void lddmm_partial(const float* __restrict__ mom,
                                                       const float* __restrict__ cp,
                                                       float* __restrict__ ws) {
    const int ib = (int)blockIdx.x / JC;
    const int jc = (int)blockIdx.x % JC;
    const int t  = (int)threadIdx.x;
    const int i0 = ib * (BI * 2) + t;     // component .x
    const int i1 = i0 + BI;               // component .y

    // i-side data packed: {i0-value, i1-value}
    v2f xi0, xi1, xi2, ci, pi0, pi1, pi2;
    {
        const float a0 = cp[i0 * 3 + 0], a1 = cp[i0 * 3 + 1], a2 = cp[i0 * 3 + 2];
        const float b0 = cp[i1 * 3 + 0], b1 = cp[i1 * 3 + 1], b2 = cp[i1 * 3 + 2];
        xi0.x = a0; xi0.y = b0;
        xi1.x = a1; xi1.y = b1;
        xi2.x = a2; xi2.y = b2;
        ci.x = COEF * (a0 * a0 + a1 * a1 + a2 * a2);
        ci.y = COEF * (b0 * b0 + b1 * b1 + b2 * b2);
        pi0.x = clamp1(mom[i0 * 3 + 0]); pi0.y = clamp1(mom[i1 * 3 + 0]);
        pi1.x = clamp1(mom[i0 * 3 + 1]); pi1.y = clamp1(mom[i1 * 3 + 1]);
        pi2.x = clamp1(mom[i0 * 3 + 2]); pi2.y = clamp1(mom[i1 * 3 + 2]);
    }

    // Stage j-chunk: shx = {M2COEF*xj, COEF*|xj|^2}, shp = {pj clamped, 0}
    __shared__ float4 shx[JLEN];
    __shared__ float4 shp[JLEN];
    if (t < JLEN) {
        const int j = jc * JLEN + t;
        const float x0 = cp[j * 3 + 0], x1 = cp[j * 3 + 1], x2 = cp[j * 3 + 2];
        shx[t] = make_float4(M2COEF * x0, M2COEF * x1, M2COEF * x2,
                             COEF * (x0 * x0 + x1 * x1 + x2 * x2));
        shp[t] = make_float4(clamp1(mom[j * 3 + 0]), clamp1(mom[j * 3 + 1]),
                             clamp1(mom[j * 3 + 2]), 0.0f);
    }
    __syncthreads();

    v2f dcp0 = vsplat(0.f), dcp1 = vsplat(0.f), dcp2 = vsplat(0.f);
    v2f wsum = vsplat(0.f);
    v2f wx0 = vsplat(0.f), wx1 = vsplat(0.f), wx2 = vsplat(0.f);

#pragma unroll 8
    for (int jj = 0; jj < JLEN; ++jj) {
        const float4 xj = shx[jj];   // wave-uniform -> LDS broadcast
        const float4 pj = shp[jj];

        // arg = ci + cj + dot(xi, M2COEF*xj) = COEF*d2  (1 pk_add + 3 pk_fma)
        v2f arg = ci + vsplat(xj.w);
        arg = pkfma(xi2, vsplat(xj.z), arg);
        arg = pkfma(xi1, vsplat(xj.y), arg);
        arg = pkfma(xi0, vsplat(xj.x), arg);
        v2f K;                               // 2 trans
        K.x = fast_exp2(arg.x);
        K.y = fast_exp2(arg.y);
        v2f pd = pi0 * vsplat(pj.x);         // 1 pk_mul + 2 pk_fma
        pd = pkfma(pi1, vsplat(pj.y), pd);
        pd = pkfma(pi2, vsplat(pj.z), pd);
        const v2f W = K * pd;                // 1 pk_mul
        dcp0 = pkfma(K, vsplat(pj.x), dcp0); // 3 pk_fma
        dcp1 = pkfma(K, vsplat(pj.y), dcp1);
        dcp2 = pkfma(K, vsplat(pj.z), dcp2);
        wsum = wsum + W;                     // 1 pk_add
        wx0 = pkfma(W, vsplat(xj.x), wx0);   // 3 pk_fma (M2COEF-scaled)
        wx1 = pkfma(W, vsplat(xj.y), wx1);
        wx2 = pkfma(W, vsplat(xj.z), wx2);
    }

    float4* oa = (float4*)(ws + ((size_t)(jc * NPTS) + i0) * 8);
    oa[0] = make_float4(dcp0.x, dcp1.x, dcp2.x, wsum.x);
    oa[1] = make_float4(wx0.x, wx1.x, wx2.x, 0.0f);
    float4* ob = (float4*)(ws + ((size_t)(jc * NPTS) + i1) * 8);
    ob[0] = make_float4(dcp0.y, dcp1.y, dcp2.y, wsum.y);
    ob[1] = make_float4(wx0.y, wx1.y, wx2.y, 0.0f);
}

// 4 threads per i: sub=(cpart,half). Each sums JC/2 chunks of one float4,
// xor-2 combines chunk halves, xor-1 hands wsum from half0 to half1.
// dmom = 100*xi*wsum - (100/M2COEF)*wxs.
__global__ __launch_bounds__(256) void lddmm_reduce(const float* __restrict__ ws,
                                                    const float* __restrict__ cp,
                                                    float* __restrict__ out) {
    const int tid   = (int)blockIdx.x * 256 + (int)threadIdx.x;
    const int i     = tid >> 2;
    const int sub   = tid & 3;
    const int half  = sub & 1;
    const int cpart = sub >> 1;

    float4 acc = make_float4(0.f, 0.f, 0.f, 0.f);
    const int c0 = cpart * (JC / 2);
#pragma unroll 4
    for (int c = c0; c < c0 + JC / 2; ++c) {
        const float4 v = ((const float4*)(ws + ((size_t)(c * NPTS) + i) * 8))[half];
        acc.x += v.x; acc.y += v.y; acc.z += v.z; acc.w += v.w;
    }
    acc.x += __shfl_xor(acc.x, 2);
    acc.y += __shfl_xor(acc.y, 2);
    acc.z += __shfl_xor(acc.z, 2);
    acc.w += __shfl_xor(acc.w, 2);
    const float wsum = __shfl_xor(acc.w, 1);
    if (sub == 0) {
        out[N3 + i * 3 + 0] = acc.x;
        out[N3 + i * 3 + 1] = acc.y;
        out[N3 + i * 3 + 2] = acc.z;
    } else if (sub == 1) {
        const float xi0 = cp[i * 3 + 0];
        const float xi1 = cp[i * 3 + 1];
        const float xi2 = cp[i * 3 + 2];
        out[i * 3 + 0] = fmaf(100.0f * xi0, wsum, -UNSC100 * acc.x);
        out[i * 3 + 1] = fmaf(100.0f * xi1, wsum, -UNSC100 * acc.y);
        out[i * 3 + 2] = fmaf(100.0f * xi2, wsum, -UNSC100 * acc.z);
    }
}

// ---- fallback (atomics into d_out) if ws_size < WS_NEEDED ----
#define FJC   32
#define FJLEN (NPTS / FJC)
__global__ __launch_bounds__(BI) void lddmm_pairs_atomic(const float* __restrict__ mom,
                                                         const float* __restrict__ cp,
                                                         float* __restrict__ out) {
    const int ib = (int)blockIdx.x / FJC;
    const int jc = (int)blockIdx.x % FJC;
    const int t  = (int)threadIdx.x;
    const int i  = ib * BI + t;

    const float xi0 = cp[i * 3 + 0], xi1 = cp[i * 3 + 1], xi2 = cp[i * 3 + 2];
    const float pi0 = clamp1(mom[i * 3 + 0]), pi1 = clamp1(mom[i * 3 + 1]),
                pi2 = clamp1(mom[i * 3 + 2]);

    __shared__ float4 shx[FJLEN];
    __shared__ float4 shp[FJLEN];
    {
        const int j = jc * FJLEN + t;
        shx[t] = make_float4(cp[j * 3 + 0], cp[j * 3 + 1], cp[j * 3 + 2], 0.0f);
        shp[t] = make_float4(clamp1(mom[j * 3 + 0]), clamp1(mom[j * 3 + 1]),
                             clamp1(mom[j * 3 + 2]), 0.0f);
    }
    __syncthreads();

    float dcp0 = 0.f, dcp1 = 0.f, dcp2 = 0.f, wsum = 0.f, wx0 = 0.f, wx1 = 0.f, wx2 = 0.f;
#pragma unroll 4
    for (int jj = 0; jj < FJLEN; ++jj) {
        const float4 xj = shx[jj];
        const float4 pj = shp[jj];
        const float dx0 = xi0 - xj.x, dx1 = xi1 - xj.y, dx2 = xi2 - xj.z;
        const float d2  = dx0 * dx0 + dx1 * dx1 + dx2 * dx2;
        const float K   = fast_exp2(d2 * COEF);
        const float pd  = pi0 * pj.x + pi1 * pj.y + pi2 * pj.z;
        const float W   = K * pd;
        dcp0 += K * pj.x; dcp1 += K * pj.y; dcp2 += K * pj.z;
        wsum += W;
        wx0 += W * xj.x; wx1 += W * xj.y; wx2 += W * xj.z;
    }
    atomicAdd(&out[i * 3 + 0], 100.0f * (xi0 * wsum - wx0));
    atomicAdd(&out[i * 3 + 1], 100.0f * (xi1 * wsum - wx1));
    atomicAdd(&out[i * 3 + 2], 100.0f * (xi2 * wsum - wx2));
    atomicAdd(&out[N3 + i * 3 + 0], dcp0);
    atomicAdd(&out[N3 + i * 3 + 1], dcp1);
    atomicAdd(&out[N3 + i * 3 + 2], dcp2);
}

extern "C" void kernel_launch(void* const* d_in, const int* in_sizes, int n_in,
                              void* d_out, int out_size, void* d_ws, size_t ws_size,
                              hipStream_t stream) {
    const float* mom = (const float*)d_in[0];
    const float* cp  = (const float*)d_in[1];
    float* out = (float*)d_out;

    if (ws_size >= WS_NEEDED) {
        float* ws = (float*)d_ws;
        hipLaunchKernelGGL(lddmm_partial, dim3(IBLK * JC), dim3(BI), 0, stream, mom, cp, ws);
        hipLaunchKernelGGL(lddmm_reduce, dim3(NPTS * 4 / 256), dim3(256), 0, stream, ws, cp, out);
    } else {
        hipMemsetAsync(out, 0, (size_t)out_size * sizeof(float), stream);
        hipLaunchKernelGGL(lddmm_pairs_atomic, dim3((NPTS / BI) * FJC), dim3(BI), 0, stream, mom, cp, out);
    }
}